// Round 7
// baseline (173.312 us; speedup 1.0000x reference)
//
#include <hip/hip_runtime.h>
#include <hip/hip_bf16.h>

#define GLOBAL_AS __attribute__((address_space(1)))
#define LDS_AS    __attribute__((address_space(3)))

typedef __bf16 bf16x8 __attribute__((ext_vector_type(8)));
typedef float  f32x4  __attribute__((ext_vector_type(4)));

constexpr int BATCH = 8192;           // M
constexpr int IN    = 1024;
constexpr int OUT   = 1024;           // N
constexpr int KDIM  = IN * 4;         // 4096 (4 "powers" per input)
constexpr int BM = 128, BN = 256, BK = 64;
constexpr int NKT  = KDIM / BK;       // 64 K-tiles
constexpr int LDSBUF = 24576;         // ushort elems per buffer: A 8192 + B 16384 (48 KB)

// round-to-nearest-even float -> bf16 bits (inputs finite)
__device__ __forceinline__ unsigned short f2bf(float f) {
    union { float f; unsigned u; } v; v.f = f;
    unsigned r = v.u + 0x7fffu + ((v.u >> 16) & 1u);
    return (unsigned short)(r >> 16);
}
__device__ __forceinline__ unsigned pk(unsigned short a, unsigned short b) {
    return (unsigned)a | ((unsigned)b << 16);
}

// B-side prep only (A-expansion fused into the gemm).
// B_big[o, 4i+k] = {W[o,i], C[o,i,1..3]} bf16; be[o] = bias[o] + sum_i C[o,i,0].
__global__ __launch_bounds__(256) void prep_b(const float* __restrict__ W,
                                              const float* __restrict__ C,
                                              const float* __restrict__ bias,
                                              unsigned short* __restrict__ Bb,
                                              float* __restrict__ be) {
    const int o = blockIdx.x, t = threadIdx.x;
    const int i0 = t * 4;
    const float4* c4 = reinterpret_cast<const float4*>(C + ((size_t)o * IN + i0) * 4);
    float4 w4 = *reinterpret_cast<const float4*>(W + (size_t)o * IN + i0);
    float wv[4] = {w4.x, w4.y, w4.z, w4.w};
    float s = 0.f;
    unsigned d[8];
#pragma unroll
    for (int j = 0; j < 4; ++j) {
        float4 c = c4[j];
        s += c.x;                                  // x^0 term -> bias
        d[2*j]   = pk(f2bf(wv[j]), f2bf(c.y));
        d[2*j+1] = pk(f2bf(c.z),   f2bf(c.w));
    }
    uint4* dst = reinterpret_cast<uint4*>(Bb + (size_t)o * KDIM + i0 * 4);
    dst[0] = make_uint4(d[0], d[1], d[2], d[3]);
    dst[1] = make_uint4(d[4], d[5], d[6], d[7]);
#pragma unroll
    for (int off = 32; off > 0; off >>= 1) s += __shfl_down(s, off, 64);
    __shared__ float red[4];
    if ((t & 63) == 0) red[t >> 6] = s;
    __syncthreads();
    if (t == 0) be[o] = bias[o] + red[0] + red[1] + red[2] + red[3];
}

// Fused KAN GEMM, UNPINNED R6 schedule + in-kernel A-expansion.
//  - B: gload_lds triple-buffer, depth-2 prefetch, counted-vmcnt boundaries.
//  - A: raw x (float4/thread/tile) -> {silu,x,x^2,x^3} -> swizzled ds_write_b128
//    into the same LDS image the unfused kernel had (reader untouched).
//  - Expansion sits in the tile's BOUNDARY SHADOW (after MFMAs, before the
//    boundary wait) with NO fences around it; compiler schedules freely.
//  - x for tile kt+2 is loaded during tile kt-1 (3-tile lookahead via xcur/xnext).
//
// vmcnt ledger (per wave; x-load position in queue is compiler-chosen, ledger is
// robust to it because x(kt+2) is always retired by the expansion's own wait
// BEFORE the boundary asm, leaving B(kt+1)x4 as the 4 oldest):
//   steady (kt<=60): queue at boundary = [B(kt+1)x4] + {x(kt+3), B(kt+2)x4} = 9
//                    -> vmcnt(5) retires exactly B(kt+1)x4.
//   kt==61: queue = [B(62)x4, B(63)x4] -> vmcnt(4).   kt==62: -> vmcnt(0).
// lgkmcnt(0) at each boundary drains this wave's A-expansion ds_writes (cheap:
// ds_reads already drained by MFMA deps); readers cross the same barrier.
__global__ __launch_bounds__(512, 2) void gemm_kan(
        const float* __restrict__ x,
        const unsigned short* __restrict__ Bb,
        const float* __restrict__ be,
        float* __restrict__ out) {
    extern __shared__ unsigned short smem[];   // 3 * 24576 ushorts = 144 KB

    const int t    = threadIdx.x;
    const int l    = blockIdx.x;               // 0..255
    const int bm   = l & 63;                   // 0..63
    const int bn   = l >> 6;                   // 0..3
    const int lane = t & 63;
    const int wave = t >> 6;                   // 0..7
    const int wr   = wave >> 2;                // 0..1 : M half
    const int wc   = wave & 3;                 // 0..3 : N quarter
    const int l15  = lane & 15;
    const int quad = lane >> 4;
    const int x7   = l15 & 7;

    // ---- B staging (gload_lds, pre-swizzled global source; LDS dest linear)
    const unsigned short* bP[4];
#pragma unroll
    for (int i = 0; i < 4; ++i) {
        int ch = i * 512 + t, r = ch >> 3, g = (ch & 7) ^ (r & 7);
        bP[i] = Bb + (size_t)(bn * BN + r) * KDIM + g * 8;
    }

    // ---- A expansion (reg -> swizzled ds_write): thread t owns row t>>2, x-quad t&3
    const int arow  = t >> 2;                  // 0..127
    const int axi   = t & 3;                   // which 4 of the 16 x's in the tile
    const int aoff0 = arow * 64 + (((axi * 2)     ^ (arow & 7)) * 8);
    const int aoff1 = arow * 64 + (((axi * 2 + 1) ^ (arow & 7)) * 8);
    const float4* xp = reinterpret_cast<const float4*>(
        x + (size_t)(bm * BM + arow) * IN + axi * 4);   // tile kt -> xp[kt*4]

    // ---- ds_read bases (ushort elements)
    const int aRd = (wr * 32 + l15) * 64;            // A region at offset 0
    const int bRd = 8192 + (wc * 64 + l15) * 64;     // B region at offset 8192

    f32x4 acc[4][4];
    const f32x4 zero = {0.f, 0.f, 0.f, 0.f};
#pragma unroll
    for (int i = 0; i < 4; ++i)
#pragma unroll
        for (int j = 0; j < 4; ++j) acc[i][j] = zero;

#define STAGE_B(tile, buf) do {                                                        \
    _Pragma("unroll")                                                                  \
    for (int i_ = 0; i_ < 4; ++i_)                                                     \
        __builtin_amdgcn_global_load_lds(                                              \
            (const GLOBAL_AS void*)(bP[i_] + (size_t)(tile) * BK),                     \
            (LDS_AS void*)(smem + (buf) * LDSBUF + 8192 + (i_ * 512 + t) * 8),         \
            16, 0, 0);                                                                 \
} while (0)

    // identical arithmetic to the original prep-A (absmax must not change)
#define STAGE_A(buf, v) do {                                                           \
    float e_[4] = {(v).x, (v).y, (v).z, (v).w};                                        \
    unsigned short o_[16];                                                             \
    _Pragma("unroll")                                                                  \
    for (int j = 0; j < 4; ++j) {                                                      \
        float xv_ = e_[j];                                                             \
        float s_  = xv_ / (1.0f + __expf(-xv_));                                       \
        float x2_ = xv_ * xv_;                                                         \
        o_[4*j+0] = f2bf(s_);                                                          \
        o_[4*j+1] = f2bf(xv_);                                                         \
        o_[4*j+2] = f2bf(x2_);                                                         \
        o_[4*j+3] = f2bf(x2_ * xv_);                                                   \
    }                                                                                  \
    unsigned short* ab_ = smem + (buf) * LDSBUF;                                       \
    *reinterpret_cast<uint4*>(ab_ + aoff0) =                                           \
        make_uint4(pk(o_[0],o_[1]), pk(o_[2],o_[3]), pk(o_[4],o_[5]), pk(o_[6],o_[7]));\
    *reinterpret_cast<uint4*>(ab_ + aoff1) =                                           \
        make_uint4(pk(o_[8],o_[9]), pk(o_[10],o_[11]), pk(o_[12],o_[13]), pk(o_[14],o_[15]));\
} while (0)

    // ---- prologue: A(0),A(1) expanded; B(0),B(1) staged; x(2) in flight.
    float4 xa   = xp[0];
    float4 xb   = xp[4];
    float4 xcur = xp[8];                       // x for tile 2
    float4 xnext = xcur;                       // rotation register
    STAGE_B(0, 0);
    STAGE_B(1, 1);
    STAGE_A(0, xa);
    STAGE_A(1, xb);
    // vmcnt(4) is robust to compiler placement of the x(2) issue: the oldest
    // 5 retired always include B(0)x4. lgkmcnt(0) drains our ds_writes.
    asm volatile("s_waitcnt vmcnt(4) lgkmcnt(0)" ::: "memory");
    __builtin_amdgcn_s_barrier();

    int cb = 0;
    for (int kt = 0; kt < NKT; ++kt) {
        const unsigned short* sb = smem + cb * LDSBUF;
        const int nb = (cb >= 1) ? cb - 1 : 2;         // buffer for tile kt+2

        if (kt + 3 < NKT) xnext = xp[(kt + 3) * 4];    // x for tile kt+3
        if (kt + 2 < NKT) STAGE_B(kt + 2, nb);

#pragma unroll
        for (int kk = 0; kk < 2; ++kk) {
            const int ck = ((kk * 4 + quad) ^ x7) * 8;
            bf16x8 af[4], bv[4];
            af[0] = *reinterpret_cast<const bf16x8*>(sb + aRd + ck);
            af[1] = *reinterpret_cast<const bf16x8*>(sb + aRd + 1024 + ck);
            af[2] = *reinterpret_cast<const bf16x8*>(sb + aRd + 4096 + ck);
            af[3] = *reinterpret_cast<const bf16x8*>(sb + aRd + 5120 + ck);
#pragma unroll
            for (int ni = 0; ni < 4; ++ni)
                bv[ni] = *reinterpret_cast<const bf16x8*>(sb + bRd + ni * 1024 + ck);
#pragma unroll
            for (int mi = 0; mi < 4; ++mi)
#pragma unroll
                for (int ni = 0; ni < 4; ++ni)
                    acc[mi][ni] = __builtin_amdgcn_mfma_f32_16x16x32_bf16(
                        af[mi], bv[ni], acc[mi][ni], 0, 0, 0);
        }

        // ---- boundary shadow: expand A(kt+2) into nb (no fences; compiler-scheduled)
        if (kt + 2 < NKT) {
            STAGE_A(nb, xcur);
            xcur = xnext;
        }

        // ---- boundary: B(kt+1) landed; our ds_writes drained; prefetch stays in flight
        if (kt < NKT - 3) {
            asm volatile("s_waitcnt vmcnt(5) lgkmcnt(0)" ::: "memory");
            __builtin_amdgcn_s_barrier();
        } else if (kt == NKT - 3) {            // kt==61: no x(64) issued this tile
            asm volatile("s_waitcnt vmcnt(4) lgkmcnt(0)" ::: "memory");
            __builtin_amdgcn_s_barrier();
        } else if (kt == NKT - 2) {            // kt==62: drain B(63)
            asm volatile("s_waitcnt vmcnt(0) lgkmcnt(0)" ::: "memory");
            __builtin_amdgcn_s_barrier();
        }
        cb = (cb == 2) ? 0 : cb + 1;
    }

#undef STAGE_A
#undef STAGE_B

    // ---- epilogue: C/D layout col = lane&15, row = quad*4 + reg
    float bev[4];
#pragma unroll
    for (int ni = 0; ni < 4; ++ni)
        bev[ni] = be[bn * BN + wc * 64 + ni * 16 + l15];

#pragma unroll
    for (int mg = 0; mg < 4; ++mg) {
        const int grow = bm * BM + (mg >> 1) * 64 + wr * 32 + (mg & 1) * 16 + quad * 4;
#pragma unroll
        for (int ni = 0; ni < 4; ++ni) {
            const int gcol = bn * BN + wc * 64 + ni * 16 + l15;
            float* po = out + (size_t)grow * OUT + gcol;
#pragma unroll
            for (int r = 0; r < 4; ++r)
                po[(size_t)r * OUT] = acc[mg][ni][r] + bev[ni];
        }
    }
}

extern "C" void kernel_launch(void* const* d_in, const int* in_sizes, int n_in,
                              void* d_out, int out_size, void* d_ws, size_t ws_size,
                              hipStream_t stream) {
    const float* x    = (const float*)d_in[0];   // [8192,1024]
    const float* W    = (const float*)d_in[1];   // [1024,1024]
    const float* C    = (const float*)d_in[2];   // [1024,1024,4]
    const float* bias = (const float*)d_in[3];   // [1024]
    float* out = (float*)d_out;

    unsigned short* Bb = (unsigned short*)d_ws;                    // 8 MB
    float*          be = (float*)(Bb + (size_t)OUT * KDIM);        // 4 KB

    constexpr int LDS_BYTES = 3 * LDSBUF * 2;                      // 147456 = 144 KB
    static bool inited = false;
    if (!inited) {
        hipFuncSetAttribute(reinterpret_cast<const void*>(&gemm_kan),
                            hipFuncAttributeMaxDynamicSharedMemorySize, LDS_BYTES);
        inited = true;
    }

    prep_b<<<dim3(1024), dim3(256), 0, stream>>>(W, C, bias, Bb, be);

    gemm_kan<<<dim3(256), dim3(512), LDS_BYTES, stream>>>(x, Bb, be, out);
}

// Round 10
// 168.788 us; speedup vs baseline: 1.0268x; 1.0268x over previous
//
#include <hip/hip_runtime.h>
#include <hip/hip_bf16.h>

#define GLOBAL_AS __attribute__((address_space(1)))
#define LDS_AS    __attribute__((address_space(3)))

typedef __bf16 bf16x8 __attribute__((ext_vector_type(8)));
typedef float  f32x4  __attribute__((ext_vector_type(4)));

constexpr int BATCH = 8192;           // M
constexpr int IN    = 1024;
constexpr int OUT   = 1024;           // N
constexpr int KDIM  = IN * 4;         // 4096 (4 "powers" per input)
constexpr int BM = 128, BN = 256, BK = 64;
constexpr int NKT  = KDIM / BK;       // 64 K-tiles
constexpr int LDSBUF = 24576;         // ushort elems per buffer: A 8192 + B 16384 (48 KB)

// round-to-nearest-even float -> bf16 bits (prep_b only; gemm uses HW pair-cvt)
__device__ __forceinline__ unsigned short f2bf(float f) {
    union { float f; unsigned u; } v; v.f = f;
    unsigned r = v.u + 0x7fffu + ((v.u >> 16) & 1u);
    return (unsigned short)(r >> 16);
}
__device__ __forceinline__ unsigned pk(unsigned short a, unsigned short b) {
    return (unsigned)a | ((unsigned)b << 16);
}
// __hip_bfloat162 -> u32 bits (x in low 16, y in high 16), alignment-safe
__device__ __forceinline__ unsigned b2u(__hip_bfloat162 h) {
    unsigned u; __builtin_memcpy(&u, &h, 4); return u;
}

// B-side prep only (A-expansion fused into the gemm).
// B_big[o, 4i+k] = {W[o,i], C[o,i,1..3]} bf16; be[o] = bias[o] + sum_i C[o,i,0].
__global__ __launch_bounds__(256) void prep_b(const float* __restrict__ W,
                                              const float* __restrict__ C,
                                              const float* __restrict__ bias,
                                              unsigned short* __restrict__ Bb,
                                              float* __restrict__ be) {
    const int o = blockIdx.x, t = threadIdx.x;
    const int i0 = t * 4;
    const float4* c4 = reinterpret_cast<const float4*>(C + ((size_t)o * IN + i0) * 4);
    float4 w4 = *reinterpret_cast<const float4*>(W + (size_t)o * IN + i0);
    float wv[4] = {w4.x, w4.y, w4.z, w4.w};
    float s = 0.f;
    unsigned d[8];
#pragma unroll
    for (int j = 0; j < 4; ++j) {
        float4 c = c4[j];
        s += c.x;                                  // x^0 term -> bias
        d[2*j]   = pk(f2bf(wv[j]), f2bf(c.y));
        d[2*j+1] = pk(f2bf(c.z),   f2bf(c.w));
    }
    uint4* dst = reinterpret_cast<uint4*>(Bb + (size_t)o * KDIM + i0 * 4);
    dst[0] = make_uint4(d[0], d[1], d[2], d[3]);
    dst[1] = make_uint4(d[4], d[5], d[6], d[7]);
#pragma unroll
    for (int off = 32; off > 0; off >>= 1) s += __shfl_down(s, off, 64);
    __shared__ float red[4];
    if ((t & 63) == 0) red[t >> 6] = s;
    __syncthreads();
    if (t == 0) be[o] = bias[o] + red[0] + red[1] + red[2] + red[3];
}

// Fused KAN GEMM, UNPINNED R6 schedule + SLIM in-kernel A-expansion.
//
// vs Round 7 (ran, 98.2us, VALUBusy 38): expansion arithmetic cut ~500 -> ~150
// VALU instrs/thread/tile:
//  - f2bf (4 ops) + pk (2 ops) per value  ->  __float22bfloat162_rn pair-convert
//    (HW v_cvt_pk_bf16_f32; x=low/y=high matches pk(lo,hi) bit-exactly)
//  - exact IEEE divide (~7-op seq)  ->  __fdividef (v_rcp + mul; <=1.5ulp,
//    invisible after bf16 RNE rounding)
// vs Round 8/9 (container failed 4x, never profiled): the two novel constructs
// (__builtin_amdgcn_rcpf, scalar __bf16 casts) are replaced by documented HIP
// API; everything else is byte-identical to R7 which ran.
//
// Schedule (unchanged from R7): B gload_lds triple-buffer depth-2, counted
// vmcnt; A-expansion in the boundary shadow, no fences; x loaded 3 tiles ahead.
// vmcnt ledger: steady boundary queue = [B(kt+1)x4] + {x(kt+3), B(kt+2)x4}
//   -> vmcnt(5); kt==61 -> vmcnt(4); kt==62 -> vmcnt(0).
// lgkmcnt(0) at each boundary drains this wave's A ds_writes; readers cross
// the same barrier one tile later.
__global__ __launch_bounds__(512, 2) void gemm_kan(
        const float* __restrict__ x,
        const unsigned short* __restrict__ Bb,
        const float* __restrict__ be,
        float* __restrict__ out) {
    extern __shared__ unsigned short smem[];   // 3 * 24576 ushorts = 144 KB

    const int t    = threadIdx.x;
    const int l    = blockIdx.x;               // 0..255
    const int bm   = l & 63;                   // 0..63
    const int bn   = l >> 6;                   // 0..3
    const int lane = t & 63;
    const int wave = t >> 6;                   // 0..7
    const int wr   = wave >> 2;                // 0..1 : M half
    const int wc   = wave & 3;                 // 0..3 : N quarter
    const int l15  = lane & 15;
    const int quad = lane >> 4;
    const int x7   = l15 & 7;

    // ---- B staging (gload_lds, pre-swizzled global source; LDS dest linear)
    const unsigned short* bP[4];
#pragma unroll
    for (int i = 0; i < 4; ++i) {
        int ch = i * 512 + t, r = ch >> 3, g = (ch & 7) ^ (r & 7);
        bP[i] = Bb + (size_t)(bn * BN + r) * KDIM + g * 8;
    }

    // ---- A expansion (reg -> swizzled ds_write): thread t owns row t>>2, x-quad t&3
    const int arow  = t >> 2;                  // 0..127
    const int axi   = t & 3;                   // which 4 of the 16 x's in the tile
    const int aoff0 = arow * 64 + (((axi * 2)     ^ (arow & 7)) * 8);
    const int aoff1 = arow * 64 + (((axi * 2 + 1) ^ (arow & 7)) * 8);
    const float4* xp = reinterpret_cast<const float4*>(
        x + (size_t)(bm * BM + arow) * IN + axi * 4);   // tile kt -> xp[kt*4]

    // ---- ds_read bases (ushort elements)
    const int aRd = (wr * 32 + l15) * 64;            // A region at offset 0
    const int bRd = 8192 + (wc * 64 + l15) * 64;     // B region at offset 8192

    f32x4 acc[4][4];
    const f32x4 zero = {0.f, 0.f, 0.f, 0.f};
#pragma unroll
    for (int i = 0; i < 4; ++i)
#pragma unroll
        for (int j = 0; j < 4; ++j) acc[i][j] = zero;

#define STAGE_B(tile, buf) do {                                                        \
    _Pragma("unroll")                                                                  \
    for (int i_ = 0; i_ < 4; ++i_)                                                     \
        __builtin_amdgcn_global_load_lds(                                              \
            (const GLOBAL_AS void*)(bP[i_] + (size_t)(tile) * BK),                     \
            (LDS_AS void*)(smem + (buf) * LDSBUF + 8192 + (i_ * 512 + t) * 8),         \
            16, 0, 0);                                                                 \
} while (0)

    // slim expansion: {silu, x, x^2, x^3} per element, HW pair-converts
#define STAGE_A(buf, v) do {                                                           \
    float e_[4] = {(v).x, (v).y, (v).z, (v).w};                                        \
    unsigned d_[8];                                                                    \
    _Pragma("unroll")                                                                  \
    for (int j = 0; j < 4; ++j) {                                                      \
        float xv_ = e_[j];                                                             \
        float s_  = __fdividef(xv_, 1.0f + __expf(-xv_));                              \
        float x2_ = xv_ * xv_;                                                         \
        float x3_ = x2_ * xv_;                                                         \
        d_[2*j]   = b2u(__float22bfloat162_rn(make_float2(s_, xv_)));                  \
        d_[2*j+1] = b2u(__float22bfloat162_rn(make_float2(x2_, x3_)));                 \
    }                                                                                  \
    unsigned short* ab_ = smem + (buf) * LDSBUF;                                       \
    *reinterpret_cast<uint4*>(ab_ + aoff0) = make_uint4(d_[0], d_[1], d_[2], d_[3]);   \
    *reinterpret_cast<uint4*>(ab_ + aoff1) = make_uint4(d_[4], d_[5], d_[6], d_[7]);   \
} while (0)

    // ---- prologue: A(0),A(1) expanded; B(0),B(1) staged; x(2) in flight.
    float4 xa   = xp[0];
    float4 xb   = xp[4];
    float4 xcur = xp[8];                       // x for tile 2
    float4 xnext = xcur;                       // rotation register
    STAGE_B(0, 0);
    STAGE_B(1, 1);
    STAGE_A(0, xa);
    STAGE_A(1, xb);
    // vmcnt(4) robust to compiler placement of the x(2) issue: the oldest
    // 5 retired always include B(0)x4. lgkmcnt(0) drains our ds_writes.
    asm volatile("s_waitcnt vmcnt(4) lgkmcnt(0)" ::: "memory");
    __builtin_amdgcn_s_barrier();

    int cb = 0;
    for (int kt = 0; kt < NKT; ++kt) {
        const unsigned short* sb = smem + cb * LDSBUF;
        const int nb = (cb >= 1) ? cb - 1 : 2;         // buffer for tile kt+2

        if (kt + 3 < NKT) xnext = xp[(kt + 3) * 4];    // x for tile kt+3
        if (kt + 2 < NKT) STAGE_B(kt + 2, nb);

#pragma unroll
        for (int kk = 0; kk < 2; ++kk) {
            const int ck = ((kk * 4 + quad) ^ x7) * 8;
            bf16x8 af[4], bv[4];
            af[0] = *reinterpret_cast<const bf16x8*>(sb + aRd + ck);
            af[1] = *reinterpret_cast<const bf16x8*>(sb + aRd + 1024 + ck);
            af[2] = *reinterpret_cast<const bf16x8*>(sb + aRd + 4096 + ck);
            af[3] = *reinterpret_cast<const bf16x8*>(sb + aRd + 5120 + ck);
#pragma unroll
            for (int ni = 0; ni < 4; ++ni)
                bv[ni] = *reinterpret_cast<const bf16x8*>(sb + bRd + ni * 1024 + ck);
#pragma unroll
            for (int mi = 0; mi < 4; ++mi)
#pragma unroll
                for (int ni = 0; ni < 4; ++ni)
                    acc[mi][ni] = __builtin_amdgcn_mfma_f32_16x16x32_bf16(
                        af[mi], bv[ni], acc[mi][ni], 0, 0, 0);
        }

        // ---- boundary shadow: expand A(kt+2) into nb (no fences; compiler-scheduled)
        if (kt + 2 < NKT) {
            STAGE_A(nb, xcur);
            xcur = xnext;
        }

        // ---- boundary: B(kt+1) landed; our ds_writes drained; prefetch stays in flight
        if (kt < NKT - 3) {
            asm volatile("s_waitcnt vmcnt(5) lgkmcnt(0)" ::: "memory");
            __builtin_amdgcn_s_barrier();
        } else if (kt == NKT - 3) {            // kt==61: no x(64) issued this tile
            asm volatile("s_waitcnt vmcnt(4) lgkmcnt(0)" ::: "memory");
            __builtin_amdgcn_s_barrier();
        } else if (kt == NKT - 2) {            // kt==62: drain B(63)
            asm volatile("s_waitcnt vmcnt(0) lgkmcnt(0)" ::: "memory");
            __builtin_amdgcn_s_barrier();
        }
        cb = (cb == 2) ? 0 : cb + 1;
    }

#undef STAGE_A
#undef STAGE_B

    // ---- epilogue: C/D layout col = lane&15, row = quad*4 + reg
    float bev[4];
#pragma unroll
    for (int ni = 0; ni < 4; ++ni)
        bev[ni] = be[bn * BN + wc * 64 + ni * 16 + l15];

#pragma unroll
    for (int mg = 0; mg < 4; ++mg) {
        const int grow = bm * BM + (mg >> 1) * 64 + wr * 32 + (mg & 1) * 16 + quad * 4;
#pragma unroll
        for (int ni = 0; ni < 4; ++ni) {
            const int gcol = bn * BN + wc * 64 + ni * 16 + l15;
            float* po = out + (size_t)grow * OUT + gcol;
#pragma unroll
            for (int r = 0; r < 4; ++r)
                po[(size_t)r * OUT] = acc[mg][ni][r] + bev[ni];
        }
    }
}

extern "C" void kernel_launch(void* const* d_in, const int* in_sizes, int n_in,
                              void* d_out, int out_size, void* d_ws, size_t ws_size,
                              hipStream_t stream) {
    const float* x    = (const float*)d_in[0];   // [8192,1024]
    const float* W    = (const float*)d_in[1];   // [1024,1024]
    const float* C    = (const float*)d_in[2];   // [1024,1024,4]
    const float* bias = (const float*)d_in[3];   // [1024]
    float* out = (float*)d_out;

    unsigned short* Bb = (unsigned short*)d_ws;                    // 8 MB
    float*          be = (float*)(Bb + (size_t)OUT * KDIM);        // 4 KB

    constexpr int LDS_BYTES = 3 * LDSBUF * 2;                      // 147456 = 144 KB
    static bool inited = false;
    if (!inited) {
        hipFuncSetAttribute(reinterpret_cast<const void*>(&gemm_kan),
                            hipFuncAttributeMaxDynamicSharedMemorySize, LDS_BYTES);
        inited = true;
    }

    prep_b<<<dim3(1024), dim3(256), 0, stream>>>(W, C, bias, Bb, be);

    gemm_kan<<<dim3(256), dim3(512), LDS_BYTES, stream>>>(x, Bb, be, out);
}

// Round 11
// 165.769 us; speedup vs baseline: 1.0455x; 1.0182x over previous
//
#include <hip/hip_runtime.h>
#include <hip/hip_bf16.h>

#define GLOBAL_AS __attribute__((address_space(1)))
#define LDS_AS    __attribute__((address_space(3)))

typedef __bf16 bf16x8 __attribute__((ext_vector_type(8)));
typedef float  f32x4  __attribute__((ext_vector_type(4)));

constexpr int BATCH = 8192;           // M
constexpr int IN    = 1024;
constexpr int OUT   = 1024;           // N
constexpr int KDIM  = IN * 4;         // 4096 (4 "powers" per input)
constexpr int BM = 128, BN = 256, BK = 64;
constexpr int NKT  = KDIM / BK;       // 64 K-tiles
constexpr int LDSBUF = 24576;         // ushort elems per buffer: A 8192 + B 16384 (48 KB)

// round-to-nearest-even float -> bf16 bits (prep_b only; gemm uses HW pair-cvt)
__device__ __forceinline__ unsigned short f2bf(float f) {
    union { float f; unsigned u; } v; v.f = f;
    unsigned r = v.u + 0x7fffu + ((v.u >> 16) & 1u);
    return (unsigned short)(r >> 16);
}
__device__ __forceinline__ unsigned pk(unsigned short a, unsigned short b) {
    return (unsigned)a | ((unsigned)b << 16);
}

// B-side prep only (A-expansion fused into the gemm).
// B_big[o, 4i+k] = {W[o,i], C[o,i,1..3]} bf16; be[o] = bias[o] + sum_i C[o,i,0].
__global__ __launch_bounds__(256) void prep_b(const float* __restrict__ W,
                                              const float* __restrict__ C,
                                              const float* __restrict__ bias,
                                              unsigned short* __restrict__ Bb,
                                              float* __restrict__ be) {
    const int o = blockIdx.x, t = threadIdx.x;
    const int i0 = t * 4;
    const float4* c4 = reinterpret_cast<const float4*>(C + ((size_t)o * IN + i0) * 4);
    float4 w4 = *reinterpret_cast<const float4*>(W + (size_t)o * IN + i0);
    float wv[4] = {w4.x, w4.y, w4.z, w4.w};
    float s = 0.f;
    unsigned d[8];
#pragma unroll
    for (int j = 0; j < 4; ++j) {
        float4 c = c4[j];
        s += c.x;                                  // x^0 term -> bias
        d[2*j]   = pk(f2bf(wv[j]), f2bf(c.y));
        d[2*j+1] = pk(f2bf(c.z),   f2bf(c.w));
    }
    uint4* dst = reinterpret_cast<uint4*>(Bb + (size_t)o * KDIM + i0 * 4);
    dst[0] = make_uint4(d[0], d[1], d[2], d[3]);
    dst[1] = make_uint4(d[4], d[5], d[6], d[7]);
#pragma unroll
    for (int off = 32; off > 0; off >>= 1) s += __shfl_down(s, off, 64);
    __shared__ float red[4];
    if ((t & 63) == 0) red[t >> 6] = s;
    __syncthreads();
    if (t == 0) be[o] = bias[o] + red[0] + red[1] + red[2] + red[3];
}

// Fused KAN GEMM, UNPINNED R6 schedule + inline-asm SLIM A-expansion.
//
// vs Round 10 (ran, 94.6us, VALUBusy 36.5 -- UNCHANGED from R7's 38): the
// intended slimming didn't materialize: __fdividef lowered to the exact
// div_scale/div_fmas/div_fixup sequence and __float22bfloat162_rn is a
// software RNE path. This round forces the slim sequence with pure-VALU
// inline asm (arithmetic only -- no memory ops, so no ordering hazards;
// compiler tracks data deps through operands):
//   silu: m = x * -log2(e); v_exp_f32 (=2^m = e^-x); 1+e; v_rcp_f32; x*r
//         -> 5 ops (2 trans), same overflow threshold (|x|=88.7) as __expf.
//   pack: v_cvt_pk_bf16_f32 (RNE; lo/hi == pk(f2bf(lo), f2bf(hi)))
//         -> 1 op per bf16 pair.
// Per element: 9 VALU; per thread/tile: ~45 instrs (measured-implied R10: ~200).
//
// Schedule (unchanged from R7/R10): B gload_lds triple-buffer depth-2, counted
// vmcnt; A-expansion in the boundary shadow, no fences; x loaded 3 tiles ahead.
// vmcnt ledger: steady boundary queue = [B(kt+1)x4] + {x(kt+3), B(kt+2)x4}
//   -> vmcnt(5); kt==61 -> vmcnt(4); kt==62 -> vmcnt(0).
// lgkmcnt(0) at each boundary drains this wave's A ds_writes; readers cross
// the same barrier one tile later.
__global__ __launch_bounds__(512, 2) void gemm_kan(
        const float* __restrict__ x,
        const unsigned short* __restrict__ Bb,
        const float* __restrict__ be,
        float* __restrict__ out) {
    extern __shared__ unsigned short smem[];   // 3 * 24576 ushorts = 144 KB

    const int t    = threadIdx.x;
    const int l    = blockIdx.x;               // 0..255
    const int bm   = l & 63;                   // 0..63
    const int bn   = l >> 6;                   // 0..3
    const int lane = t & 63;
    const int wave = t >> 6;                   // 0..7
    const int wr   = wave >> 2;                // 0..1 : M half
    const int wc   = wave & 3;                 // 0..3 : N quarter
    const int l15  = lane & 15;
    const int quad = lane >> 4;
    const int x7   = l15 & 7;

    // ---- B staging (gload_lds, pre-swizzled global source; LDS dest linear)
    const unsigned short* bP[4];
#pragma unroll
    for (int i = 0; i < 4; ++i) {
        int ch = i * 512 + t, r = ch >> 3, g = (ch & 7) ^ (r & 7);
        bP[i] = Bb + (size_t)(bn * BN + r) * KDIM + g * 8;
    }

    // ---- A expansion (reg -> swizzled ds_write): thread t owns row t>>2, x-quad t&3
    const int arow  = t >> 2;                  // 0..127
    const int axi   = t & 3;                   // which 4 of the 16 x's in the tile
    const int aoff0 = arow * 64 + (((axi * 2)     ^ (arow & 7)) * 8);
    const int aoff1 = arow * 64 + (((axi * 2 + 1) ^ (arow & 7)) * 8);
    const float4* xp = reinterpret_cast<const float4*>(
        x + (size_t)(bm * BM + arow) * IN + axi * 4);   // tile kt -> xp[kt*4]

    // ---- ds_read bases (ushort elements)
    const int aRd = (wr * 32 + l15) * 64;            // A region at offset 0
    const int bRd = 8192 + (wc * 64 + l15) * 64;     // B region at offset 8192

    f32x4 acc[4][4];
    const f32x4 zero = {0.f, 0.f, 0.f, 0.f};
#pragma unroll
    for (int i = 0; i < 4; ++i)
#pragma unroll
        for (int j = 0; j < 4; ++j) acc[i][j] = zero;

#define STAGE_B(tile, buf) do {                                                        \
    _Pragma("unroll")                                                                  \
    for (int i_ = 0; i_ < 4; ++i_)                                                     \
        __builtin_amdgcn_global_load_lds(                                              \
            (const GLOBAL_AS void*)(bP[i_] + (size_t)(tile) * BK),                     \
            (LDS_AS void*)(smem + (buf) * LDSBUF + 8192 + (i_ * 512 + t) * 8),         \
            16, 0, 0);                                                                 \
} while (0)

    // slim expansion: {silu, x, x^2, x^3}, 9 VALU/element via inline-asm VOP1/VOP3
#define STAGE_A(buf, v) do {                                                           \
    float e_[4] = {(v).x, (v).y, (v).z, (v).w};                                        \
    unsigned d_[8];                                                                    \
    _Pragma("unroll")                                                                  \
    for (int j = 0; j < 4; ++j) {                                                      \
        float xv_ = e_[j];                                                             \
        float m_  = xv_ * -1.44269504088896f;       /* -x*log2(e) */                   \
        float ex_, r_;                                                                 \
        asm("v_exp_f32 %0, %1" : "=v"(ex_) : "v"(m_));   /* 2^m = e^-x */              \
        float a_  = 1.0f + ex_;                                                        \
        asm("v_rcp_f32 %0, %1" : "=v"(r_) : "v"(a_));                                  \
        float s_  = xv_ * r_;                                                          \
        float x2_ = xv_ * xv_;                                                         \
        float x3_ = x2_ * xv_;                                                         \
        asm("v_cvt_pk_bf16_f32 %0, %1, %2" : "=v"(d_[2*j])   : "v"(s_),  "v"(xv_));    \
        asm("v_cvt_pk_bf16_f32 %0, %1, %2" : "=v"(d_[2*j+1]) : "v"(x2_), "v"(x3_));    \
    }                                                                                  \
    unsigned short* ab_ = smem + (buf) * LDSBUF;                                       \
    *reinterpret_cast<uint4*>(ab_ + aoff0) = make_uint4(d_[0], d_[1], d_[2], d_[3]);   \
    *reinterpret_cast<uint4*>(ab_ + aoff1) = make_uint4(d_[4], d_[5], d_[6], d_[7]);   \
} while (0)

    // ---- prologue: A(0),A(1) expanded; B(0),B(1) staged; x(2) in flight.
    float4 xa   = xp[0];
    float4 xb   = xp[4];
    float4 xcur = xp[8];                       // x for tile 2
    float4 xnext = xcur;                       // rotation register
    STAGE_B(0, 0);
    STAGE_B(1, 1);
    STAGE_A(0, xa);
    STAGE_A(1, xb);
    // vmcnt(4) robust to compiler placement of the x(2) issue: the oldest
    // 5 retired always include B(0)x4. lgkmcnt(0) drains our ds_writes.
    asm volatile("s_waitcnt vmcnt(4) lgkmcnt(0)" ::: "memory");
    __builtin_amdgcn_s_barrier();

    int cb = 0;
    for (int kt = 0; kt < NKT; ++kt) {
        const unsigned short* sb = smem + cb * LDSBUF;
        const int nb = (cb >= 1) ? cb - 1 : 2;         // buffer for tile kt+2

        if (kt + 3 < NKT) xnext = xp[(kt + 3) * 4];    // x for tile kt+3
        if (kt + 2 < NKT) STAGE_B(kt + 2, nb);

#pragma unroll
        for (int kk = 0; kk < 2; ++kk) {
            const int ck = ((kk * 4 + quad) ^ x7) * 8;
            bf16x8 af[4], bv[4];
            af[0] = *reinterpret_cast<const bf16x8*>(sb + aRd + ck);
            af[1] = *reinterpret_cast<const bf16x8*>(sb + aRd + 1024 + ck);
            af[2] = *reinterpret_cast<const bf16x8*>(sb + aRd + 4096 + ck);
            af[3] = *reinterpret_cast<const bf16x8*>(sb + aRd + 5120 + ck);
#pragma unroll
            for (int ni = 0; ni < 4; ++ni)
                bv[ni] = *reinterpret_cast<const bf16x8*>(sb + bRd + ni * 1024 + ck);
#pragma unroll
            for (int mi = 0; mi < 4; ++mi)
#pragma unroll
                for (int ni = 0; ni < 4; ++ni)
                    acc[mi][ni] = __builtin_amdgcn_mfma_f32_16x16x32_bf16(
                        af[mi], bv[ni], acc[mi][ni], 0, 0, 0);
        }

        // ---- boundary shadow: expand A(kt+2) into nb (no fences; compiler-scheduled)
        if (kt + 2 < NKT) {
            STAGE_A(nb, xcur);
            xcur = xnext;
        }

        // ---- boundary: B(kt+1) landed; our ds_writes drained; prefetch stays in flight
        if (kt < NKT - 3) {
            asm volatile("s_waitcnt vmcnt(5) lgkmcnt(0)" ::: "memory");
            __builtin_amdgcn_s_barrier();
        } else if (kt == NKT - 3) {            // kt==61: no x(64) issued this tile
            asm volatile("s_waitcnt vmcnt(4) lgkmcnt(0)" ::: "memory");
            __builtin_amdgcn_s_barrier();
        } else if (kt == NKT - 2) {            // kt==62: drain B(63)
            asm volatile("s_waitcnt vmcnt(0) lgkmcnt(0)" ::: "memory");
            __builtin_amdgcn_s_barrier();
        }
        cb = (cb == 2) ? 0 : cb + 1;
    }

#undef STAGE_A
#undef STAGE_B

    // ---- epilogue: C/D layout col = lane&15, row = quad*4 + reg
    float bev[4];
#pragma unroll
    for (int ni = 0; ni < 4; ++ni)
        bev[ni] = be[bn * BN + wc * 64 + ni * 16 + l15];

#pragma unroll
    for (int mg = 0; mg < 4; ++mg) {
        const int grow = bm * BM + (mg >> 1) * 64 + wr * 32 + (mg & 1) * 16 + quad * 4;
#pragma unroll
        for (int ni = 0; ni < 4; ++ni) {
            const int gcol = bn * BN + wc * 64 + ni * 16 + l15;
            float* po = out + (size_t)grow * OUT + gcol;
#pragma unroll
            for (int r = 0; r < 4; ++r)
                po[(size_t)r * OUT] = acc[mg][ni][r] + bev[ni];
        }
    }
}

extern "C" void kernel_launch(void* const* d_in, const int* in_sizes, int n_in,
                              void* d_out, int out_size, void* d_ws, size_t ws_size,
                              hipStream_t stream) {
    const float* x    = (const float*)d_in[0];   // [8192,1024]
    const float* W    = (const float*)d_in[1];   // [1024,1024]
    const float* C    = (const float*)d_in[2];   // [1024,1024,4]
    const float* bias = (const float*)d_in[3];   // [1024]
    float* out = (float*)d_out;

    unsigned short* Bb = (unsigned short*)d_ws;                    // 8 MB
    float*          be = (float*)(Bb + (size_t)OUT * KDIM);        // 4 KB

    constexpr int LDS_BYTES = 3 * LDSBUF * 2;                      // 147456 = 144 KB
    static bool inited = false;
    if (!inited) {
        hipFuncSetAttribute(reinterpret_cast<const void*>(&gemm_kan),
                            hipFuncAttributeMaxDynamicSharedMemorySize, LDS_BYTES);
        inited = true;
    }

    prep_b<<<dim3(1024), dim3(256), 0, stream>>>(W, C, bias, Bb, be);

    gemm_kan<<<dim3(256), dim3(512), LDS_BYTES, stream>>>(x, Bb, be, out);
}